// Round 5
// baseline (91.180 us; speedup 1.0000x reference)
//
#include <hip/hip_runtime.h>
#include <math.h>

#define D 128
#define NPARAMS 16
#define H 256
#define XCOLS (D + NPARAMS)   // 144
#define BATCH 4096
#define NTOT (BATCH * D)      // 524288
#define NS 8                  // samples per MLP block
#define NSP (NS + 1)          // padded LDS stride (kills store bank conflicts)

#define INV_2PI_F 0.15915494309189535f
#define OUT_SCALE 2.5132741228718345f   // 2*pi / 2.5

// ---------------- weight pre-pack: pw[k4][j][kk] = W[j][4*k4+kk] -------------
// Makes MLP weight loads coalesced: lane j loads float4 at (k4*H + j)*16 ->
// consecutive lanes, consecutive 16B.

__global__ __launch_bounds__(256) void pack_kernel(
    const float* __restrict__ w_in, const float* __restrict__ w0,
    const float* __restrict__ w1,   const float* __restrict__ w_out,
    float* __restrict__ pw_in, float* __restrict__ pw0,
    float* __restrict__ pw1,   float* __restrict__ pwo)
{
    int t = blockIdx.x * 256 + threadIdx.x;   // 0..65535
    {
        int j = t >> 8, k = t & 255;
        int dst = (k >> 2) * (H * 4) + j * 4 + (k & 3);
        pw0[dst] = w0[t];
        pw1[dst] = w1[t];
        pwo[dst] = w_out[t];
    }
    if (t < H * NPARAMS) {
        int j = t >> 4, k = t & 15;
        pw_in[(k >> 2) * (H * 4) + j * 4 + (k & 3)] = w_in[t];
    }
}

// ---------------- MLP: params(16) -> 256 -> 256 -> 256 -> coef(256) ----------

#define LAYER256P(PW4, BP, SRC) {                                      \
    float bb = (BP)[j];                                                \
    _Pragma("unroll") for (int s = 0; s < NS; ++s) acc[s] = bb;        \
    const float4* w4 = (PW4) + j;                                      \
    _Pragma("unroll 4") for (int k4 = 0; k4 < H / 4; ++k4) {           \
        float4 wv = w4[k4 * H];                                        \
        int k = k4 * 4;                                                \
        _Pragma("unroll") for (int s = 0; s < NS; ++s)                 \
            acc[s] = fmaf(wv.x, SRC[k][s], acc[s]);                    \
        _Pragma("unroll") for (int s = 0; s < NS; ++s)                 \
            acc[s] = fmaf(wv.y, SRC[k + 1][s], acc[s]);                \
        _Pragma("unroll") for (int s = 0; s < NS; ++s)                 \
            acc[s] = fmaf(wv.z, SRC[k + 2][s], acc[s]);                \
        _Pragma("unroll") for (int s = 0; s < NS; ++s)                 \
            acc[s] = fmaf(wv.w, SRC[k + 3][s], acc[s]);                \
    }                                                                  \
}

__global__ __launch_bounds__(256) void mlp_kernel(
    const float* __restrict__ x,
    const float4* __restrict__ pw_in, const float* __restrict__ b_in,
    const float4* __restrict__ pw0,   const float* __restrict__ b0,
    const float4* __restrict__ pw1,   const float* __restrict__ b1,
    const float4* __restrict__ pwo,   const float* __restrict__ b_out,
    float* __restrict__ w2buf, float* __restrict__ cbuf)
{
    __shared__ float hA[H][NSP];
    __shared__ float hB[H][NSP];
    const int j = threadIdx.x;
    const int bbase = blockIdx.x * NS;

    if (j < NPARAMS * NS) {
        int k = j / NS, s = j % NS;
        hA[k][s] = x[(bbase + s) * XCOLS + D + k];
    }
    __syncthreads();

    float acc[NS];

    // layer in: 16 -> 256, relu   (hA -> hB), packed weights, 4 k4-chunks
    {
        float bb = b_in[j];
        #pragma unroll
        for (int s = 0; s < NS; ++s) acc[s] = bb;
        const float4* w4 = pw_in + j;
        #pragma unroll
        for (int k4 = 0; k4 < NPARAMS / 4; ++k4) {
            float4 wv = w4[k4 * H];
            int k = k4 * 4;
            #pragma unroll
            for (int s = 0; s < NS; ++s) acc[s] = fmaf(wv.x, hA[k][s], acc[s]);
            #pragma unroll
            for (int s = 0; s < NS; ++s) acc[s] = fmaf(wv.y, hA[k + 1][s], acc[s]);
            #pragma unroll
            for (int s = 0; s < NS; ++s) acc[s] = fmaf(wv.z, hA[k + 2][s], acc[s]);
            #pragma unroll
            for (int s = 0; s < NS; ++s) acc[s] = fmaf(wv.w, hA[k + 3][s], acc[s]);
        }
        #pragma unroll
        for (int s = 0; s < NS; ++s) hB[j][s] = fmaxf(acc[s], 0.f);
    }
    __syncthreads();

    LAYER256P(pw0, b0, hB);
    #pragma unroll
    for (int s = 0; s < NS; ++s) hA[j][s] = fmaxf(acc[s], 0.f);
    __syncthreads();

    LAYER256P(pw1, b1, hA);
    #pragma unroll
    for (int s = 0; s < NS; ++s) hB[j][s] = fmaxf(acc[s], 0.f);
    __syncthreads();

    LAYER256P(pwo, b_out, hB);
    #pragma unroll
    for (int s = 0; s < NS; ++s) {
        float coef = acc[s];
        int b = bbase + s;
        if (j < D) {
            float om = fmaf(coef, 1.5f, 0.5f);          // omega0
            w2buf[b * D + j] = om * om * INV_2PI_F;     // omega0^2 / (2*pi)
        } else {
            cbuf[b * D + (j - D)] = coef;               // coupling (identity affine)
        }
    }
}

// ---------------- ODE: revolution-domain RK4, 2 samples per wave -------------

__device__ __forceinline__ float rot_from_lower(float v) {  // lane n <- lane (n-1)&63
    return __int_as_float(__builtin_amdgcn_mov_dpp(__float_as_int(v), 0x13C, 0xF, 0xF, false)); // wave_ror:1
}
__device__ __forceinline__ float rot_from_upper(float v) {  // lane n <- lane (n+1)&63
    return __int_as_float(__builtin_amdgcn_mov_dpp(__float_as_int(v), 0x134, 0xF, 0xF, false)); // wave_rol:1
}

__global__ __launch_bounds__(256) void ode_kernel(
    const float* __restrict__ x,
    const float* __restrict__ w2buf,
    const float* __restrict__ cbuf,
    float* __restrict__ out,
    int nstep, float dt)
{
    const int lane = threadIdx.x & 63;
    const int wid  = threadIdx.x >> 6;
    const int bA   = blockIdx.x * 8 + wid * 2;   // two consecutive samples

    float th0[2], th1[2], v0[2], v1[2];
    float nw0[2], nw1[2], c0[2], c1[2], cl[2];

    #pragma unroll
    for (int s = 0; s < 2; ++s) {
        int b  = bA + s;
        int i0 = b * D + 2 * lane;
        float2 xi  = *reinterpret_cast<const float2*>(&x[b * XCOLS + 2 * lane]);
        th0[s] = xi.x - 0.5f;            // phi0 = x - 1/2 (revolutions)
        th1[s] = xi.y - 0.5f;
        v0[s] = 0.f; v1[s] = 0.f;
        float2 w2p = *reinterpret_cast<const float2*>(&w2buf[i0]);
        float2 cp  = *reinterpret_cast<const float2*>(&cbuf[i0]);
        nw0[s] = -w2p.x; nw1[s] = -w2p.y;
        c0[s] = cp.x;    c1[s] = cp.y;
        cl[s] = cbuf[(i0 + NTOT - 1) % NTOT];   // flat-roll left coupling of osc 2l
    }

    auto deriv = [&](const float t0[2], const float t1[2], float a0[2], float a1[2]) {
        #pragma unroll
        for (int s = 0; s < 2; ++s) {
            float L0 = rot_from_lower(t1[s]);   // phi of osc 2l-1 (wraps 0 -> 127)
            float R1 = rot_from_upper(t0[s]);   // phi of osc 2l+2 (wraps 63 -> 0)
            float s0 = __builtin_amdgcn_sinf(t0[s]);   // sin(2pi*phi), raw v_sin_f32
            float s1 = __builtin_amdgcn_sinf(t1[s]);
            float dd  = t1[s] - t0[s];
            float cpl = c0[s] * dd;
            a0[s] = fmaf(s0, nw0[s], fmaf(cl[s], L0 - t0[s],  cpl));
            a1[s] = fmaf(s1, nw1[s], fmaf(c1[s], R1 - t1[s], -cpl));
        }
    };

    const float hdt   = 0.5f * dt;
    const float sixth = dt * (1.0f / 6.0f);

    for (int it = 0; it < nstep; ++it) {
        float a1_0[2], a1_1[2];
        deriv(th0, th1, a1_0, a1_1);

        float t2_0[2], t2_1[2], k2_0[2], k2_1[2];
        #pragma unroll
        for (int s = 0; s < 2; ++s) {
            t2_0[s] = fmaf(hdt, v0[s], th0[s]);   t2_1[s] = fmaf(hdt, v1[s], th1[s]);
            k2_0[s] = fmaf(hdt, a1_0[s], v0[s]);  k2_1[s] = fmaf(hdt, a1_1[s], v1[s]);
        }
        float a2_0[2], a2_1[2];
        deriv(t2_0, t2_1, a2_0, a2_1);

        float t3_0[2], t3_1[2], k3_0[2], k3_1[2];
        #pragma unroll
        for (int s = 0; s < 2; ++s) {
            t3_0[s] = fmaf(hdt, k2_0[s], th0[s]); t3_1[s] = fmaf(hdt, k2_1[s], th1[s]);
            k3_0[s] = fmaf(hdt, a2_0[s], v0[s]);  k3_1[s] = fmaf(hdt, a2_1[s], v1[s]);
        }
        float a3_0[2], a3_1[2];
        deriv(t3_0, t3_1, a3_0, a3_1);

        float t4_0[2], t4_1[2], k4_0[2], k4_1[2];
        #pragma unroll
        for (int s = 0; s < 2; ++s) {
            t4_0[s] = fmaf(dt, k3_0[s], th0[s]);  t4_1[s] = fmaf(dt, k3_1[s], th1[s]);
            k4_0[s] = fmaf(dt, a3_0[s], v0[s]);   k4_1[s] = fmaf(dt, a3_1[s], v1[s]);
        }
        float a4_0[2], a4_1[2];
        deriv(t4_0, t4_1, a4_0, a4_1);

        #pragma unroll
        for (int s = 0; s < 2; ++s) {
            th0[s] += sixth * (v0[s] + 2.f * (k2_0[s] + k3_0[s]) + k4_0[s]);
            th1[s] += sixth * (v1[s] + 2.f * (k2_1[s] + k3_1[s]) + k4_1[s]);
            v0[s]  += sixth * (a1_0[s] + 2.f * (a2_0[s] + a3_0[s]) + a4_0[s]);
            v1[s]  += sixth * (a1_1[s] + 2.f * (a2_1[s] + a3_1[s]) + a4_1[s]);
        }
    }

    #pragma unroll
    for (int s = 0; s < 2; ++s) {
        int i0 = (bA + s) * D + 2 * lane;
        float2 o = make_float2(th0[s] * OUT_SCALE, th1[s] * OUT_SCALE);
        *reinterpret_cast<float2*>(&out[i0]) = o;
    }
}

extern "C" void kernel_launch(void* const* d_in, const int* in_sizes, int n_in,
                              void* d_out, int out_size, void* d_ws, size_t ws_size,
                              hipStream_t stream) {
    const float* x     = (const float*)d_in[0];
    const float* w_in  = (const float*)d_in[1];
    const float* b_in  = (const float*)d_in[2];
    const float* w0    = (const float*)d_in[3];
    const float* b0    = (const float*)d_in[4];
    const float* w1    = (const float*)d_in[5];
    const float* b1    = (const float*)d_in[6];
    const float* w_out = (const float*)d_in[7];
    const float* b_out = (const float*)d_in[8];

    float* w2buf = (float*)d_ws;                  // omega0^2/(2pi), NTOT floats
    float* cbuf  = w2buf + NTOT;                  // coupling, NTOT floats
    float* pw_in = cbuf + NTOT;                   // packed w_in, 4096
    float* pw0   = pw_in + H * NPARAMS;           // packed w0, 65536
    float* pw1   = pw0 + H * H;                   // packed w1, 65536
    float* pwo   = pw1 + H * H;                   // packed w_out, 65536
    float* out   = (float*)d_out;

    pack_kernel<<<H * H / 256, 256, 0, stream>>>(w_in, w0, w1, w_out,
                                                 pw_in, pw0, pw1, pwo);

    mlp_kernel<<<BATCH / NS, 256, 0, stream>>>(
        x, (const float4*)pw_in, b_in, (const float4*)pw0, b0,
        (const float4*)pw1, b1, (const float4*)pwo, b_out, w2buf, cbuf);

    const int nstep = 64;
    const float dtf = (float)((59.0 / 30.0) / nstep);
    ode_kernel<<<BATCH / 8, 256, 0, stream>>>(x, w2buf, cbuf, out, nstep, dtf);
}

// Round 6
// 79.542 us; speedup vs baseline: 1.1463x; 1.1463x over previous
//
#include <hip/hip_runtime.h>
#include <math.h>

#define D 128
#define NPARAMS 16
#define H 256
#define XCOLS (D + NPARAMS)   // 144
#define BATCH 4096
#define NTOT (BATCH * D)      // 524288
#define NS 8                  // samples per MLP block

#define INV_2PI_F 0.15915494309189535f
#define OUT_SCALE 2.5132741228718345f   // 2*pi / 2.5

// ---------------- weight pre-pack: pw[k4][j][kk] = W[j][4*k4+kk] -------------
// Lane j loads float4 at (k4*H + j)*16 -> consecutive lanes, consecutive 16B.

__global__ __launch_bounds__(256) void pack_kernel(
    const float* __restrict__ w_in, const float* __restrict__ w0,
    const float* __restrict__ w1,   const float* __restrict__ w_out,
    float* __restrict__ pw_in, float* __restrict__ pw0,
    float* __restrict__ pw1,   float* __restrict__ pwo)
{
    int t = blockIdx.x * 256 + threadIdx.x;   // 0..65535
    {
        int j = t >> 8, k = t & 255;
        int dst = (k >> 2) * (H * 4) + j * 4 + (k & 3);
        pw0[dst] = w0[t];
        pw1[dst] = w1[t];
        pwo[dst] = w_out[t];
    }
    if (t < H * NPARAMS) {
        int j = t >> 4, k = t & 15;
        pw_in[(k >> 2) * (H * 4) + j * 4 + (k & 3)] = w_in[t];
    }
}

// ---------------- MLP: params(16) -> 256 -> 256 -> 256 -> coef(256) ----------
// Activations in LDS as [s][k]: stores coalesced (lane j -> consecutive),
// reads are uniform-address ds_read_b128 broadcasts. Weights streamed through
// a depth-4 register prefetch ring to hide L2 latency at 2 waves/SIMD.

template<int K4N>
__device__ __forceinline__ void layer_fwd(
    const float4* __restrict__ pw, const float* __restrict__ bias,
    const float (*__restrict__ src)[H], float* __restrict__ acc, int j)
{
    float bb = bias[j];
    #pragma unroll
    for (int s = 0; s < NS; ++s) acc[s] = bb;

    const float4* w4 = pw + j;
    float4 wbuf[4];
    #pragma unroll
    for (int p = 0; p < 4 && p < K4N; ++p) wbuf[p] = w4[p * H];

    #pragma unroll 4
    for (int k4 = 0; k4 < K4N; ++k4) {
        float4 wv = wbuf[k4 & 3];
        if (k4 + 4 < K4N) wbuf[k4 & 3] = w4[(k4 + 4) * H];
        #pragma unroll
        for (int s = 0; s < NS; ++s) {
            float4 av = reinterpret_cast<const float4*>(src[s])[k4];  // broadcast
            acc[s] = fmaf(wv.x, av.x, acc[s]);
            acc[s] = fmaf(wv.y, av.y, acc[s]);
            acc[s] = fmaf(wv.z, av.z, acc[s]);
            acc[s] = fmaf(wv.w, av.w, acc[s]);
        }
    }
}

__global__ __launch_bounds__(256) void mlp_kernel(
    const float* __restrict__ x,
    const float4* __restrict__ pw_in, const float* __restrict__ b_in,
    const float4* __restrict__ pw0,   const float* __restrict__ b0,
    const float4* __restrict__ pw1,   const float* __restrict__ b1,
    const float4* __restrict__ pwo,   const float* __restrict__ b_out,
    float* __restrict__ w2buf, float* __restrict__ cbuf)
{
    __shared__ float hA[NS][H];
    __shared__ float hB[NS][H];
    const int j = threadIdx.x;
    const int bbase = blockIdx.x * NS;

    // stage params into hA[s][k], k < 16 (128 threads)
    if (j < NPARAMS * NS) {
        int s = j >> 4, k = j & 15;
        hA[s][k] = x[(bbase + s) * XCOLS + D + k];
    }
    __syncthreads();

    float acc[NS];

    layer_fwd<NPARAMS / 4>(pw_in, b_in, hA, acc, j);
    #pragma unroll
    for (int s = 0; s < NS; ++s) hB[s][j] = fmaxf(acc[s], 0.f);
    __syncthreads();

    layer_fwd<H / 4>(pw0, b0, hB, acc, j);
    #pragma unroll
    for (int s = 0; s < NS; ++s) hA[s][j] = fmaxf(acc[s], 0.f);
    __syncthreads();

    layer_fwd<H / 4>(pw1, b1, hA, acc, j);
    #pragma unroll
    for (int s = 0; s < NS; ++s) hB[s][j] = fmaxf(acc[s], 0.f);
    __syncthreads();

    layer_fwd<H / 4>(pwo, b_out, hB, acc, j);
    #pragma unroll
    for (int s = 0; s < NS; ++s) {
        float coef = acc[s];
        int b = bbase + s;
        if (j < D) {
            float om = fmaf(coef, 1.5f, 0.5f);          // omega0
            w2buf[b * D + j] = om * om * INV_2PI_F;     // omega0^2 / (2*pi)
        } else {
            cbuf[b * D + (j - D)] = coef;               // coupling (identity affine)
        }
    }
}

// ---------------- ODE: revolution-domain RK4, 2 samples per wave -------------

__device__ __forceinline__ float rot_from_lower(float v) {  // lane n <- lane (n-1)&63
    return __int_as_float(__builtin_amdgcn_mov_dpp(__float_as_int(v), 0x13C, 0xF, 0xF, false)); // wave_ror:1
}
__device__ __forceinline__ float rot_from_upper(float v) {  // lane n <- lane (n+1)&63
    return __int_as_float(__builtin_amdgcn_mov_dpp(__float_as_int(v), 0x134, 0xF, 0xF, false)); // wave_rol:1
}

__global__ __launch_bounds__(256) void ode_kernel(
    const float* __restrict__ x,
    const float* __restrict__ w2buf,
    const float* __restrict__ cbuf,
    float* __restrict__ out,
    int nstep, float dt)
{
    const int lane = threadIdx.x & 63;
    const int wid  = threadIdx.x >> 6;
    const int bA   = blockIdx.x * 8 + wid * 2;   // two consecutive samples

    float th0[2], th1[2], v0[2], v1[2];
    float nw0[2], nw1[2], c0[2], c1[2], cl[2];

    #pragma unroll
    for (int s = 0; s < 2; ++s) {
        int b  = bA + s;
        int i0 = b * D + 2 * lane;
        float2 xi  = *reinterpret_cast<const float2*>(&x[b * XCOLS + 2 * lane]);
        th0[s] = xi.x - 0.5f;            // phi0 = x - 1/2 (revolutions)
        th1[s] = xi.y - 0.5f;
        v0[s] = 0.f; v1[s] = 0.f;
        float2 w2p = *reinterpret_cast<const float2*>(&w2buf[i0]);
        float2 cp  = *reinterpret_cast<const float2*>(&cbuf[i0]);
        nw0[s] = -w2p.x; nw1[s] = -w2p.y;
        c0[s] = cp.x;    c1[s] = cp.y;
        cl[s] = cbuf[(i0 + NTOT - 1) % NTOT];   // flat-roll left coupling of osc 2l
    }

    auto deriv = [&](const float t0[2], const float t1[2], float a0[2], float a1[2]) {
        #pragma unroll
        for (int s = 0; s < 2; ++s) {
            float L0 = rot_from_lower(t1[s]);   // phi of osc 2l-1 (wraps 0 -> 127)
            float R1 = rot_from_upper(t0[s]);   // phi of osc 2l+2 (wraps 63 -> 0)
            float s0 = __builtin_amdgcn_sinf(t0[s]);   // sin(2pi*phi), raw v_sin_f32
            float s1 = __builtin_amdgcn_sinf(t1[s]);
            float dd  = t1[s] - t0[s];
            float cpl = c0[s] * dd;
            a0[s] = fmaf(s0, nw0[s], fmaf(cl[s], L0 - t0[s],  cpl));
            a1[s] = fmaf(s1, nw1[s], fmaf(c1[s], R1 - t1[s], -cpl));
        }
    };

    const float hdt   = 0.5f * dt;
    const float sixth = dt * (1.0f / 6.0f);

    for (int it = 0; it < nstep; ++it) {
        float a1_0[2], a1_1[2];
        deriv(th0, th1, a1_0, a1_1);

        float t2_0[2], t2_1[2], k2_0[2], k2_1[2];
        #pragma unroll
        for (int s = 0; s < 2; ++s) {
            t2_0[s] = fmaf(hdt, v0[s], th0[s]);   t2_1[s] = fmaf(hdt, v1[s], th1[s]);
            k2_0[s] = fmaf(hdt, a1_0[s], v0[s]);  k2_1[s] = fmaf(hdt, a1_1[s], v1[s]);
        }
        float a2_0[2], a2_1[2];
        deriv(t2_0, t2_1, a2_0, a2_1);

        float t3_0[2], t3_1[2], k3_0[2], k3_1[2];
        #pragma unroll
        for (int s = 0; s < 2; ++s) {
            t3_0[s] = fmaf(hdt, k2_0[s], th0[s]); t3_1[s] = fmaf(hdt, k2_1[s], th1[s]);
            k3_0[s] = fmaf(hdt, a2_0[s], v0[s]);  k3_1[s] = fmaf(hdt, a2_1[s], v1[s]);
        }
        float a3_0[2], a3_1[2];
        deriv(t3_0, t3_1, a3_0, a3_1);

        float t4_0[2], t4_1[2], k4_0[2], k4_1[2];
        #pragma unroll
        for (int s = 0; s < 2; ++s) {
            t4_0[s] = fmaf(dt, k3_0[s], th0[s]);  t4_1[s] = fmaf(dt, k3_1[s], th1[s]);
            k4_0[s] = fmaf(dt, a3_0[s], v0[s]);   k4_1[s] = fmaf(dt, a3_1[s], v1[s]);
        }
        float a4_0[2], a4_1[2];
        deriv(t4_0, t4_1, a4_0, a4_1);

        #pragma unroll
        for (int s = 0; s < 2; ++s) {
            th0[s] += sixth * (v0[s] + 2.f * (k2_0[s] + k3_0[s]) + k4_0[s]);
            th1[s] += sixth * (v1[s] + 2.f * (k2_1[s] + k3_1[s]) + k4_1[s]);
            v0[s]  += sixth * (a1_0[s] + 2.f * (a2_0[s] + a3_0[s]) + a4_0[s]);
            v1[s]  += sixth * (a1_1[s] + 2.f * (a2_1[s] + a3_1[s]) + a4_1[s]);
        }
    }

    #pragma unroll
    for (int s = 0; s < 2; ++s) {
        int i0 = (bA + s) * D + 2 * lane;
        float2 o = make_float2(th0[s] * OUT_SCALE, th1[s] * OUT_SCALE);
        *reinterpret_cast<float2*>(&out[i0]) = o;
    }
}

extern "C" void kernel_launch(void* const* d_in, const int* in_sizes, int n_in,
                              void* d_out, int out_size, void* d_ws, size_t ws_size,
                              hipStream_t stream) {
    const float* x     = (const float*)d_in[0];
    const float* w_in  = (const float*)d_in[1];
    const float* b_in  = (const float*)d_in[2];
    const float* w0    = (const float*)d_in[3];
    const float* b0    = (const float*)d_in[4];
    const float* w1    = (const float*)d_in[5];
    const float* b1    = (const float*)d_in[6];
    const float* w_out = (const float*)d_in[7];
    const float* b_out = (const float*)d_in[8];

    float* w2buf = (float*)d_ws;                  // omega0^2/(2pi), NTOT floats
    float* cbuf  = w2buf + NTOT;                  // coupling, NTOT floats
    float* pw_in = cbuf + NTOT;                   // packed w_in, 4096
    float* pw0   = pw_in + H * NPARAMS;           // packed w0, 65536
    float* pw1   = pw0 + H * H;                   // packed w1, 65536
    float* pwo   = pw1 + H * H;                   // packed w_out, 65536
    float* out   = (float*)d_out;

    pack_kernel<<<H * H / 256, 256, 0, stream>>>(w_in, w0, w1, w_out,
                                                 pw_in, pw0, pw1, pwo);

    mlp_kernel<<<BATCH / NS, 256, 0, stream>>>(
        x, (const float4*)pw_in, b_in, (const float4*)pw0, b0,
        (const float4*)pw1, b1, (const float4*)pwo, b_out, w2buf, cbuf);

    const int nstep = 40;
    const float dtf = (float)((59.0 / 30.0) / nstep);
    ode_kernel<<<BATCH / 8, 256, 0, stream>>>(x, w2buf, cbuf, out, nstep, dtf);
}